// Round 1
// baseline (832.273 us; speedup 1.0000x reference)
//
#include <hip/hip_runtime.h>
#include <cstdint>

// LlamaAttention prefill: x[T,D] -> QKV gemm -> RoPE -> causal GQA flash attn -> O gemm
// T=4096 (B=4 x S=1024), D=4096, N=32 q-heads, K=8 kv-heads, H=128.
// All matmuls bf16 MFMA 16x16x32, fp32 accumulate. Workspace: 168 MB.

typedef unsigned short u16;
typedef short bf16x8 __attribute__((ext_vector_type(8)));
typedef float f32x4 __attribute__((ext_vector_type(4)));

#define L2E 1.44269504088896340736f

static __device__ __forceinline__ u16 f2bf(float f) {
  union { float f; unsigned u; } v; v.f = f;
  unsigned r = (v.u + 0x7fffu + ((v.u >> 16) & 1u)) >> 16;
  return (u16)r;
}
static __device__ __forceinline__ float bf2f(u16 h) {
  union { unsigned u; float f; } v; v.u = ((unsigned)h) << 16;
  return v.f;
}

typedef __attribute__((address_space(1))) const unsigned int gas_u32;
typedef __attribute__((address_space(3))) unsigned int las_u32;
// async global->LDS, 16B per lane; LDS dest must be wave-uniform base (+lane*16).
static __device__ __forceinline__ void glds16(const void* g, const void* l) {
  __builtin_amdgcn_global_load_lds((gas_u32*)(uintptr_t)g,
                                   (las_u32*)(unsigned)(uintptr_t)l, 16, 0, 0);
}

// ---------------- fp32 -> bf16 elementwise ----------------
__global__ __launch_bounds__(256) void cvt_kernel(const float4* __restrict__ in,
                                                  uint2* __restrict__ out, int n4) {
  int i = blockIdx.x * 256 + threadIdx.x;
  if (i < n4) {
    float4 v = in[i];
    uint2 r;
    r.x = (unsigned)f2bf(v.x) | ((unsigned)f2bf(v.y) << 16);
    r.y = (unsigned)f2bf(v.z) | ((unsigned)f2bf(v.w) << 16);
    out[i] = r;
  }
}

// ---------------- fp32 [R][C] -> bf16 [C][R] tiled transpose ----------------
__global__ __launch_bounds__(256) void tcvt_kernel(const float* __restrict__ in,
                                                   u16* __restrict__ out, int R, int C) {
  __shared__ float tile[32][33];
  int tx = threadIdx.x, ty = threadIdx.y;  // block (32,8)
  int r0 = blockIdx.y * 32, c0 = blockIdx.x * 32;
#pragma unroll
  for (int j = 0; j < 4; ++j)
    tile[ty + j * 8][tx] = in[(size_t)(r0 + ty + j * 8) * C + c0 + tx];
  __syncthreads();
#pragma unroll
  for (int j = 0; j < 4; ++j)
    out[(size_t)(c0 + ty + j * 8) * R + r0 + tx] = f2bf(tile[tx][ty + j * 8]);
}

// ---------------- NT GEMM: C[M,N] = A[M,K] * B[N,K]^T (bf16 in, fp32 acc) --------
// 128x128 tile, BK=64, 256 thr = 4 waves (2x2 of 64x64), global_load_lds staging
// with XOR chunk swizzle: phys_chunk = logical_chunk ^ (row&7) -> 2-way-free ds_read_b128.
template <int BF16OUT>
__global__ __launch_bounds__(256, 2) void gemm_nt(const u16* __restrict__ A,
                                                  const u16* __restrict__ Bm,
                                                  void* __restrict__ Cp,
                                                  int M, int N, int Kd) {
  __shared__ u16 Al[128 * 64];
  __shared__ u16 Bl[128 * 64];
  const int tid = threadIdx.x;
  const int w = tid >> 6, lane = tid & 63;
  const int ln15 = lane & 15, quad = lane >> 4;
  const int wm = w & 1, wn = w >> 1;
  const int m0 = blockIdx.y * 128, n0 = blockIdx.x * 128;

  // staging: inst q covers rows q*32 + w*8 + lane/8, phys chunk = lane&7
  const int rA = w * 8 + (lane >> 3);
  const int cA = (((lane & 7) ^ (rA & 7)) << 3);
  const u16* aptr = A + (size_t)(m0 + rA) * Kd + cA;
  const u16* bptr = Bm + (size_t)(n0 + rA) * Kd + cA;

  f32x4 acc[4][4];
#pragma unroll
  for (int i = 0; i < 4; ++i)
#pragma unroll
    for (int j = 0; j < 4; ++j) acc[i][j] = f32x4{0.f, 0.f, 0.f, 0.f};

  for (int k0 = 0; k0 < Kd; k0 += 64) {
    __syncthreads();
#pragma unroll
    for (int q = 0; q < 4; ++q) {
      glds16(aptr + (size_t)q * 32 * Kd, &Al[(q * 32 + w * 8) * 64]);
      glds16(bptr + (size_t)q * 32 * Kd, &Bl[(q * 32 + w * 8) * 64]);
    }
    aptr += 64; bptr += 64;
    __syncthreads();
#pragma unroll
    for (int ks = 0; ks < 2; ++ks) {
      bf16x8 af[4], bfr[4];
#pragma unroll
      for (int t = 0; t < 4; ++t) {
        int ra = wm * 64 + t * 16 + ln15;
        int pa = (ks * 4 + quad) ^ (ra & 7);
        af[t] = *(const bf16x8*)&Al[ra * 64 + pa * 8];
        int rb = wn * 64 + t * 16 + ln15;
        int pb = (ks * 4 + quad) ^ (rb & 7);
        bfr[t] = *(const bf16x8*)&Bl[rb * 64 + pb * 8];
      }
#pragma unroll
      for (int mt = 0; mt < 4; ++mt)
#pragma unroll
        for (int nt = 0; nt < 4; ++nt)
          acc[mt][nt] =
              __builtin_amdgcn_mfma_f32_16x16x32_bf16(af[mt], bfr[nt], acc[mt][nt], 0, 0, 0);
    }
  }

#pragma unroll
  for (int mt = 0; mt < 4; ++mt) {
#pragma unroll
    for (int nt = 0; nt < 4; ++nt) {
      int row = m0 + wm * 64 + mt * 16 + quad * 4;
      int col = n0 + wn * 64 + nt * 16 + ln15;
#pragma unroll
      for (int r = 0; r < 4; ++r) {
        float v = acc[mt][nt][r];
        if (BF16OUT)
          ((u16*)Cp)[(size_t)(row + r) * N + col] = f2bf(v);
        else
          ((float*)Cp)[(size_t)(row + r) * N + col] = v;
      }
    }
  }
}

// ---------------- RoPE in-place on q (cols 0..4095) and k (cols 4096..5119) ------
// Also folds softmax scale 1/sqrt(128) into q.
__global__ __launch_bounds__(256) void rope_kernel(u16* __restrict__ qkv,
                                                   const int* __restrict__ pos, int total) {
  int idx = blockIdx.x * 256 + threadIdx.x;
  if (idx >= total) return;          // total = T * 40 * 64
  int t = idx / 2560;
  int rem = idx - t * 2560;
  int head = rem >> 6;               // 0..39 (32 q heads + 8 k heads)
  int i = rem & 63;                  // rotation pair index
  float p = (float)pos[t];
  float inv = powf(10000.0f, -(float)i * (1.0f / 64.0f));  // theta^{-2i/H}
  float f = p * inv;
  float s, c;
  sincosf(f, &s, &c);
  int colbase = (head < 32) ? head * 128 : (4096 + (head - 32) * 128);
  u16* base = qkv + (size_t)t * 6144 + colbase;
  float x1 = bf2f(base[i]), x2 = bf2f(base[i + 64]);
  float o1 = x1 * c - x2 * s;
  float o2 = x2 * c + x1 * s;
  if (head < 32) { o1 *= 0.08838834764831845f; o2 *= 0.08838834764831845f; }
  base[i] = f2bf(o1);
  base[i + 64] = f2bf(o2);
}

// ---------------- Flash attention, causal, GQA ----------------
// grid = B*N*(S/64); block 256 = 4 waves; wave w owns q-rows w*16..w*16+15.
// K tile [64][128] via swizzled global_load_lds; V tile transposed [128][72] scalar;
// online softmax in registers (rows live in 16-lane quads); P->LDS->A-layout for PV.
__global__ __launch_bounds__(256, 2) void attn_kernel(const u16* __restrict__ qkv,
                                                      u16* __restrict__ outp) {
  __shared__ u16 Klds[64 * 128];
  __shared__ u16 Vtlds[128 * 72];
  __shared__ u16 Plds[4 * 16 * 72];

  const int bx = blockIdx.x;
  const int qb = bx & 15;
  const int n = (bx >> 4) & 31;
  const int b = bx >> 9;
  const int kh = n >> 2;             // GQA: 4 q heads per kv head

  const int tid = threadIdx.x;
  const int w = tid >> 6;
  const int lane = tid & 63;
  const int ln15 = lane & 15;
  const int quad = lane >> 4;

  const int ldq = 6144;
  const int seq0 = b << 10;
  const int q0 = seq0 + qb * 64;

  const u16* Qg = qkv + n * 128;
  const u16* Kg = qkv + 4096 + kh * 128;
  const u16* Vg = qkv + 5120 + kh * 128;

  // Q fragments (A-layout: m=ln15, k=quad*8+j), q pre-scaled in rope
  bf16x8 qf[4];
  {
    const u16* qrow = Qg + (size_t)(q0 + w * 16 + ln15) * ldq + quad * 8;
#pragma unroll
    for (int ks = 0; ks < 4; ++ks) qf[ks] = *(const bf16x8*)(qrow + ks * 32);
  }

  f32x4 o[8];
#pragma unroll
  for (int i = 0; i < 8; ++i) o[i] = f32x4{0.f, 0.f, 0.f, 0.f};
  float m_r[4] = {-INFINITY, -INFINITY, -INFINITY, -INFINITY};
  float l_r[4] = {0.f, 0.f, 0.f, 0.f};

  const int krow = w * 4 + (lane >> 4);
  const int kcol = (((lane & 15) ^ (krow & 7)) << 3);

  for (int kt = 0; kt <= qb; ++kt) {
    __syncthreads();  // previous tile fully consumed
    {
      const u16* kbase = Kg + (size_t)(seq0 + kt * 64 + krow) * ldq + kcol;
#pragma unroll
      for (int q = 0; q < 4; ++q)
        glds16(kbase + (size_t)q * 16 * ldq, &Klds[(q * 16 + w * 4) * 128]);
    }
    {
      const int vs = tid >> 5;       // 0..7
      const int h0 = tid & 31;
#pragma unroll
      for (int p = 0; p < 8; ++p) {
        int s = p * 8 + vs;
        const u16* vrow = Vg + (size_t)(seq0 + kt * 64 + s) * ldq;
#pragma unroll
        for (int j = 0; j < 4; ++j) {
          int h = h0 + j * 32;
          Vtlds[h * 72 + s] = vrow[h];
        }
      }
    }
    __syncthreads();  // tiles visible (drains vmcnt for global_load_lds)

    // S = Q K^T : 16x64 per wave
    f32x4 sfr[4];
#pragma unroll
    for (int c = 0; c < 4; ++c) {
      f32x4 acc = f32x4{0.f, 0.f, 0.f, 0.f};
#pragma unroll
      for (int ks = 0; ks < 4; ++ks) {
        int rr = c * 16 + ln15;
        int ph = (ks * 4 + quad) ^ (rr & 7);
        bf16x8 kf = *(const bf16x8*)&Klds[rr * 128 + ph * 8];
        acc = __builtin_amdgcn_mfma_f32_16x16x32_bf16(qf[ks], kf, acc, 0, 0, 0);
      }
      sfr[c] = acc;
    }

    if (kt == qb) {  // diagonal tile: mask col>row (offsets cancel)
#pragma unroll
      for (int c = 0; c < 4; ++c) {
        int col = c * 16 + ln15;
#pragma unroll
        for (int r = 0; r < 4; ++r)
          if (col > w * 16 + quad * 4 + r) sfr[c][r] = -INFINITY;
      }
    }

    // online softmax; row (quad*4+r) spans the 16 lanes of a quad
    float alpha[4];
#pragma unroll
    for (int r = 0; r < 4; ++r) {
      float mx = fmaxf(fmaxf(sfr[0][r], sfr[1][r]), fmaxf(sfr[2][r], sfr[3][r]));
      mx = fmaxf(mx, __shfl_xor(mx, 1));
      mx = fmaxf(mx, __shfl_xor(mx, 2));
      mx = fmaxf(mx, __shfl_xor(mx, 4));
      mx = fmaxf(mx, __shfl_xor(mx, 8));
      float mnew = fmaxf(m_r[r], mx);
      alpha[r] = exp2f((m_r[r] - mnew) * L2E);
      m_r[r] = mnew;
      float rs = 0.f;
#pragma unroll
      for (int c = 0; c < 4; ++c) {
        float pv = exp2f((sfr[c][r] - mnew) * L2E);
        sfr[c][r] = pv;
        rs += pv;
      }
      rs += __shfl_xor(rs, 1);
      rs += __shfl_xor(rs, 2);
      rs += __shfl_xor(rs, 4);
      rs += __shfl_xor(rs, 8);
      l_r[r] = alpha[r] * l_r[r] + rs;
    }

#pragma unroll
    for (int ht = 0; ht < 8; ++ht)
#pragma unroll
      for (int r = 0; r < 4; ++r) o[ht][r] *= alpha[r];

    // P: C-layout -> LDS -> A-layout (bf16)
#pragma unroll
    for (int c = 0; c < 4; ++c)
#pragma unroll
      for (int r = 0; r < 4; ++r)
        Plds[w * 1152 + (quad * 4 + r) * 72 + c * 16 + ln15] = f2bf(sfr[c][r]);

    asm volatile("s_waitcnt lgkmcnt(0)" ::: "memory");

    bf16x8 pf[2];
#pragma unroll
    for (int ks = 0; ks < 2; ++ks)
      pf[ks] = *(const bf16x8*)&Plds[w * 1152 + ln15 * 72 + ks * 32 + quad * 8];
#pragma unroll
    for (int ht = 0; ht < 8; ++ht) {
#pragma unroll
      for (int ks = 0; ks < 2; ++ks) {
        bf16x8 vf = *(const bf16x8*)&Vtlds[(ht * 16 + ln15) * 72 + ks * 32 + quad * 8];
        o[ht] = __builtin_amdgcn_mfma_f32_16x16x32_bf16(pf[ks], vf, o[ht], 0, 0, 0);
      }
    }
  }

#pragma unroll
  for (int r = 0; r < 4; ++r) l_r[r] = 1.f / l_r[r];
#pragma unroll
  for (int ht = 0; ht < 8; ++ht)
#pragma unroll
    for (int r = 0; r < 4; ++r)
      outp[(size_t)(q0 + w * 16 + quad * 4 + r) * 4096 + n * 128 + ht * 16 + ln15] =
          f2bf(o[ht][r] * l_r[r]);
}

// ---------------- host ----------------
extern "C" void kernel_launch(void* const* d_in, const int* in_sizes, int n_in,
                              void* d_out, int out_size, void* d_ws, size_t ws_size,
                              hipStream_t stream) {
  const float* x = (const float*)d_in[0];
  const int* posi = (const int*)d_in[1];
  const float* Wq = (const float*)d_in[2];
  const float* Wk = (const float*)d_in[3];
  const float* Wv = (const float*)d_in[4];
  const float* Wo = (const float*)d_in[5];
  float* out = (float*)d_out;
  char* ws = (char*)d_ws;

  // workspace layout (bytes); attn reuses xb region (disjoint lifetimes). 168 MB total.
  u16* xb = (u16*)(ws);                         // [4096][4096] bf16, 33.5 MB
  u16* Wt = (u16*)(ws + 33554432);              // [6144][4096] bf16 (Wq^T|Wk^T|Wv^T), 50.3 MB
  u16* WoT = (u16*)(ws + 83886080);             // [4096][4096] bf16 (Wo^T), 33.5 MB
  u16* qkv = (u16*)(ws + 117440512);            // [4096][6144] bf16, 50.3 MB
  u16* attn = xb;                               // [4096][4096] bf16 (after x consumed)

  cvt_kernel<<<16384, 256, 0, stream>>>((const float4*)x, (uint2*)xb, 4194304);
  tcvt_kernel<<<dim3(128, 128), dim3(32, 8), 0, stream>>>(Wq, Wt, 4096, 4096);
  tcvt_kernel<<<dim3(32, 128), dim3(32, 8), 0, stream>>>(Wk, Wt + (size_t)4096 * 4096, 4096, 1024);
  tcvt_kernel<<<dim3(32, 128), dim3(32, 8), 0, stream>>>(Wv, Wt + (size_t)5120 * 4096, 4096, 1024);
  tcvt_kernel<<<dim3(128, 128), dim3(32, 8), 0, stream>>>(Wo, WoT, 4096, 4096);

  gemm_nt<1><<<dim3(48, 32), 256, 0, stream>>>(xb, Wt, qkv, 4096, 6144, 4096);
  rope_kernel<<<40960, 256, 0, stream>>>(qkv, posi, 10485760);
  attn_kernel<<<2048, 256, 0, stream>>>(qkv, attn);
  gemm_nt<0><<<dim3(32, 32), 256, 0, stream>>>(attn, WoT, out, 4096, 4096, 4096);
}

// Round 2
// 768.044 us; speedup vs baseline: 1.0836x; 1.0836x over previous
//
#include <hip/hip_runtime.h>
#include <cstdint>

// LlamaAttention prefill: x[T,D] -> QKV gemm -> RoPE -> causal GQA flash attn -> O gemm
// T=4096 (B=4 x S=1024), D=4096, N=32 q-heads, K=8 kv-heads, H=128.
// All matmuls bf16 MFMA 16x16x32, fp32 accumulate. Workspace: 168 MB.

typedef unsigned short u16;
typedef short bf16x8 __attribute__((ext_vector_type(8)));
typedef float f32x4 __attribute__((ext_vector_type(4)));

#define L2E 1.44269504088896340736f

static __device__ __forceinline__ u16 f2bf(float f) {
  union { float f; unsigned u; } v; v.f = f;
  unsigned r = (v.u + 0x7fffu + ((v.u >> 16) & 1u)) >> 16;
  return (u16)r;
}
static __device__ __forceinline__ float bf2f(u16 h) {
  union { unsigned u; float f; } v; v.u = ((unsigned)h) << 16;
  return v.f;
}

typedef __attribute__((address_space(1))) const unsigned int gas_u32;
typedef __attribute__((address_space(3))) unsigned int las_u32;
// async global->LDS, 16B per lane; LDS dest must be wave-uniform base (+lane*16).
static __device__ __forceinline__ void glds16(const void* g, const void* l) {
  __builtin_amdgcn_global_load_lds((gas_u32*)(uintptr_t)g,
                                   (las_u32*)(unsigned)(uintptr_t)l, 16, 0, 0);
}

// ---------------- fp32 -> bf16 elementwise ----------------
__global__ __launch_bounds__(256) void cvt_kernel(const float4* __restrict__ in,
                                                  uint2* __restrict__ out, int n4) {
  int i = blockIdx.x * 256 + threadIdx.x;
  if (i < n4) {
    float4 v = in[i];
    uint2 r;
    r.x = (unsigned)f2bf(v.x) | ((unsigned)f2bf(v.y) << 16);
    r.y = (unsigned)f2bf(v.z) | ((unsigned)f2bf(v.w) << 16);
    out[i] = r;
  }
}

// ---------------- fp32 [R][C] -> bf16 [C][R] tiled transpose ----------------
__global__ __launch_bounds__(256) void tcvt_kernel(const float* __restrict__ in,
                                                   u16* __restrict__ out, int R, int C) {
  __shared__ float tile[32][33];
  int tx = threadIdx.x, ty = threadIdx.y;  // block (32,8)
  int r0 = blockIdx.y * 32, c0 = blockIdx.x * 32;
#pragma unroll
  for (int j = 0; j < 4; ++j)
    tile[ty + j * 8][tx] = in[(size_t)(r0 + ty + j * 8) * C + c0 + tx];
  __syncthreads();
#pragma unroll
  for (int j = 0; j < 4; ++j)
    out[(size_t)(c0 + ty + j * 8) * R + r0 + tx] = f2bf(tile[tx][ty + j * 8]);
}

// ---------------- NT GEMM: C[M,N] = A[M,K] * B[N,K]^T (bf16 in, fp32 acc) --------
// 128x128 tile, BK=64, 256 thr = 4 waves (2x2 of 64x64), global_load_lds staging
// with XOR chunk swizzle: phys_chunk = logical_chunk ^ (row&7) -> 2-way-free ds_read_b128.
template <int BF16OUT>
__global__ __launch_bounds__(256, 2) void gemm_nt(const u16* __restrict__ A,
                                                  const u16* __restrict__ Bm,
                                                  void* __restrict__ Cp,
                                                  int M, int N, int Kd) {
  __shared__ u16 Al[128 * 64];
  __shared__ u16 Bl[128 * 64];
  const int tid = threadIdx.x;
  const int w = tid >> 6, lane = tid & 63;
  const int ln15 = lane & 15, quad = lane >> 4;
  const int wm = w & 1, wn = w >> 1;
  const int m0 = blockIdx.y * 128, n0 = blockIdx.x * 128;

  // staging: inst q covers rows q*32 + w*8 + lane/8, phys chunk = lane&7
  const int rA = w * 8 + (lane >> 3);
  const int cA = (((lane & 7) ^ (rA & 7)) << 3);
  const u16* aptr = A + (size_t)(m0 + rA) * Kd + cA;
  const u16* bptr = Bm + (size_t)(n0 + rA) * Kd + cA;

  f32x4 acc[4][4];
#pragma unroll
  for (int i = 0; i < 4; ++i)
#pragma unroll
    for (int j = 0; j < 4; ++j) acc[i][j] = f32x4{0.f, 0.f, 0.f, 0.f};

  for (int k0 = 0; k0 < Kd; k0 += 64) {
    __syncthreads();
#pragma unroll
    for (int q = 0; q < 4; ++q) {
      glds16(aptr + (size_t)q * 32 * Kd, &Al[(q * 32 + w * 8) * 64]);
      glds16(bptr + (size_t)q * 32 * Kd, &Bl[(q * 32 + w * 8) * 64]);
    }
    aptr += 64; bptr += 64;
    __syncthreads();
#pragma unroll
    for (int ks = 0; ks < 2; ++ks) {
      bf16x8 af[4], bfr[4];
#pragma unroll
      for (int t = 0; t < 4; ++t) {
        int ra = wm * 64 + t * 16 + ln15;
        int pa = (ks * 4 + quad) ^ (ra & 7);
        af[t] = *(const bf16x8*)&Al[ra * 64 + pa * 8];
        int rb = wn * 64 + t * 16 + ln15;
        int pb = (ks * 4 + quad) ^ (rb & 7);
        bfr[t] = *(const bf16x8*)&Bl[rb * 64 + pb * 8];
      }
#pragma unroll
      for (int mt = 0; mt < 4; ++mt)
#pragma unroll
        for (int nt = 0; nt < 4; ++nt)
          acc[mt][nt] =
              __builtin_amdgcn_mfma_f32_16x16x32_bf16(af[mt], bfr[nt], acc[mt][nt], 0, 0, 0);
    }
  }

#pragma unroll
  for (int mt = 0; mt < 4; ++mt) {
#pragma unroll
    for (int nt = 0; nt < 4; ++nt) {
      int row = m0 + wm * 64 + mt * 16 + quad * 4;
      int col = n0 + wn * 64 + nt * 16 + ln15;
#pragma unroll
      for (int r = 0; r < 4; ++r) {
        float v = acc[mt][nt][r];
        if (BF16OUT)
          ((u16*)Cp)[(size_t)(row + r) * N + col] = f2bf(v);
        else
          ((float*)Cp)[(size_t)(row + r) * N + col] = v;
      }
    }
  }
}

// ---------------- RoPE in-place on q (cols 0..4095) and k (cols 4096..5119) ------
// Also folds softmax scale 1/sqrt(128) into q.
__global__ __launch_bounds__(256) void rope_kernel(u16* __restrict__ qkv,
                                                   const int* __restrict__ pos, int total) {
  int idx = blockIdx.x * 256 + threadIdx.x;
  if (idx >= total) return;          // total = T * 40 * 64
  int t = idx / 2560;
  int rem = idx - t * 2560;
  int head = rem >> 6;               // 0..39 (32 q heads + 8 k heads)
  int i = rem & 63;                  // rotation pair index
  float p = (float)pos[t];
  // theta^{-2i/H} = 2^(-i * log2(10000)/64)
  float inv = exp2f(-0.20751874963942190927f * (float)i);
  float f = p * inv;
  float s, c;
  sincosf(f, &s, &c);
  int colbase = (head < 32) ? head * 128 : (4096 + (head - 32) * 128);
  u16* base = qkv + (size_t)t * 6144 + colbase;
  float x1 = bf2f(base[i]), x2 = bf2f(base[i + 64]);
  float o1 = x1 * c - x2 * s;
  float o2 = x2 * c + x1 * s;
  if (head < 32) { o1 *= 0.08838834764831845f; o2 *= 0.08838834764831845f; }
  base[i] = f2bf(o1);
  base[i + 64] = f2bf(o2);
}

// ---------------- Flash attention, causal, GQA ----------------
// grid = B*N*(S/64); block 256 = 4 waves; wave w owns q-rows w*16..w*16+15.
// K tile [64][128] via swizzled global_load_lds; V tile transposed [128][72] via
// vectorized global b128 loads + conflict-free packed b32 LDS writes;
// online softmax in registers (rows live in 16-lane quads); P->LDS->A-layout for PV.
__global__ __launch_bounds__(256, 3) void attn_kernel(const u16* __restrict__ qkv,
                                                      u16* __restrict__ outp) {
  __shared__ u16 Klds[64 * 128];
  __shared__ u16 Vtlds[128 * 72];
  __shared__ u16 Plds[4 * 16 * 72];

  const int bx = blockIdx.x;
  const int qb = 15 - (bx & 15);     // heavy (large-qb) blocks dispatch first
  const int n = (bx >> 4) & 31;
  const int b = bx >> 9;
  const int kh = n >> 2;             // GQA: 4 q heads per kv head

  const int tid = threadIdx.x;
  const int w = tid >> 6;
  const int lane = tid & 63;
  const int ln15 = lane & 15;
  const int quad = lane >> 4;

  const int ldq = 6144;
  const int seq0 = b << 10;
  const int q0 = seq0 + qb * 64;

  const u16* Qg = qkv + n * 128;
  const u16* Kg = qkv + 4096 + kh * 128;
  const u16* Vg = qkv + 5120 + kh * 128;

  // Q fragments (A-layout: m=ln15, k=quad*8+j), q pre-scaled in rope
  bf16x8 qf[4];
  {
    const u16* qrow = Qg + (size_t)(q0 + w * 16 + ln15) * ldq + quad * 8;
#pragma unroll
    for (int ks = 0; ks < 4; ++ks) qf[ks] = *(const bf16x8*)(qrow + ks * 32);
  }

  f32x4 o[8];
#pragma unroll
  for (int i = 0; i < 8; ++i) o[i] = f32x4{0.f, 0.f, 0.f, 0.f};
  float m_r[4] = {-INFINITY, -INFINITY, -INFINITY, -INFINITY};
  float l_r[4] = {0.f, 0.f, 0.f, 0.f};

  const int krow = w * 4 + (lane >> 4);
  const int kcol = (((lane & 15) ^ (krow & 7)) << 3);

  // V staging geometry: lane covers rows (s0, s0+1) x 16 h's starting at hb
  const int vs0 = (lane & 31) * 2;
  const int vhb = w * 32 + (lane >> 5) * 16;

  for (int kt = 0; kt <= qb; ++kt) {
    __syncthreads();  // previous tile fully consumed
    {
      const u16* kbase = Kg + (size_t)(seq0 + kt * 64 + krow) * ldq + kcol;
#pragma unroll
      for (int q = 0; q < 4; ++q)
        glds16(kbase + (size_t)q * 16 * ldq, &Klds[(q * 16 + w * 4) * 128]);
    }
    {
      // V transpose: vector global loads -> packed pair writes (2 lanes/bank = free)
      const u16* v0 = Vg + (size_t)(seq0 + kt * 64 + vs0) * ldq + vhb;
      union { uint4 v[2]; u16 s[16]; } ra, rb;
      ra.v[0] = *(const uint4*)v0;
      ra.v[1] = *(const uint4*)(v0 + 8);
      rb.v[0] = *(const uint4*)(v0 + ldq);
      rb.v[1] = *(const uint4*)(v0 + ldq + 8);
#pragma unroll
      for (int j = 0; j < 16; ++j) {
        unsigned pk = (unsigned)ra.s[j] | ((unsigned)rb.s[j] << 16);
        *(unsigned*)&Vtlds[(vhb + j) * 72 + vs0] = pk;
      }
    }
    __syncthreads();  // tiles visible (drains vmcnt for global_load_lds)

    // S = Q K^T : 16x64 per wave
    f32x4 sfr[4];
#pragma unroll
    for (int c = 0; c < 4; ++c) {
      f32x4 acc = f32x4{0.f, 0.f, 0.f, 0.f};
#pragma unroll
      for (int ks = 0; ks < 4; ++ks) {
        int rr = c * 16 + ln15;
        int ph = (ks * 4 + quad) ^ (rr & 7);
        bf16x8 kf = *(const bf16x8*)&Klds[rr * 128 + ph * 8];
        acc = __builtin_amdgcn_mfma_f32_16x16x32_bf16(qf[ks], kf, acc, 0, 0, 0);
      }
      sfr[c] = acc;
    }

    if (kt == qb) {  // diagonal tile: mask col>row (offsets cancel)
#pragma unroll
      for (int c = 0; c < 4; ++c) {
        int col = c * 16 + ln15;
#pragma unroll
        for (int r = 0; r < 4; ++r)
          if (col > w * 16 + quad * 4 + r) sfr[c][r] = -INFINITY;
      }
    }

    // online softmax; row (quad*4+r) spans the 16 lanes of a quad
    float alpha[4];
#pragma unroll
    for (int r = 0; r < 4; ++r) {
      float mx = fmaxf(fmaxf(sfr[0][r], sfr[1][r]), fmaxf(sfr[2][r], sfr[3][r]));
      mx = fmaxf(mx, __shfl_xor(mx, 1));
      mx = fmaxf(mx, __shfl_xor(mx, 2));
      mx = fmaxf(mx, __shfl_xor(mx, 4));
      mx = fmaxf(mx, __shfl_xor(mx, 8));
      float mnew = fmaxf(m_r[r], mx);
      alpha[r] = exp2f((m_r[r] - mnew) * L2E);
      m_r[r] = mnew;
      float rs = 0.f;
#pragma unroll
      for (int c = 0; c < 4; ++c) {
        float pv = exp2f((sfr[c][r] - mnew) * L2E);
        sfr[c][r] = pv;
        rs += pv;
      }
      rs += __shfl_xor(rs, 1);
      rs += __shfl_xor(rs, 2);
      rs += __shfl_xor(rs, 4);
      rs += __shfl_xor(rs, 8);
      l_r[r] = alpha[r] * l_r[r] + rs;
    }

#pragma unroll
    for (int ht = 0; ht < 8; ++ht)
#pragma unroll
      for (int r = 0; r < 4; ++r) o[ht][r] *= alpha[r];

    // P: C-layout -> LDS -> A-layout (bf16)
#pragma unroll
    for (int c = 0; c < 4; ++c)
#pragma unroll
      for (int r = 0; r < 4; ++r)
        Plds[w * 1152 + (quad * 4 + r) * 72 + c * 16 + ln15] = f2bf(sfr[c][r]);

    asm volatile("s_waitcnt lgkmcnt(0)" ::: "memory");

    bf16x8 pf[2];
#pragma unroll
    for (int ks = 0; ks < 2; ++ks)
      pf[ks] = *(const bf16x8*)&Plds[w * 1152 + ln15 * 72 + ks * 32 + quad * 8];
#pragma unroll
    for (int ht = 0; ht < 8; ++ht) {
#pragma unroll
      for (int ks = 0; ks < 2; ++ks) {
        bf16x8 vf = *(const bf16x8*)&Vtlds[(ht * 16 + ln15) * 72 + ks * 32 + quad * 8];
        o[ht] = __builtin_amdgcn_mfma_f32_16x16x32_bf16(pf[ks], vf, o[ht], 0, 0, 0);
      }
    }
  }

#pragma unroll
  for (int r = 0; r < 4; ++r) l_r[r] = 1.f / l_r[r];
#pragma unroll
  for (int ht = 0; ht < 8; ++ht)
#pragma unroll
    for (int r = 0; r < 4; ++r)
      outp[(size_t)(q0 + w * 16 + quad * 4 + r) * 4096 + n * 128 + ht * 16 + ln15] =
          f2bf(o[ht][r] * l_r[r]);
}

// ---------------- host ----------------
extern "C" void kernel_launch(void* const* d_in, const int* in_sizes, int n_in,
                              void* d_out, int out_size, void* d_ws, size_t ws_size,
                              hipStream_t stream) {
  const float* x = (const float*)d_in[0];
  const int* posi = (const int*)d_in[1];
  const float* Wq = (const float*)d_in[2];
  const float* Wk = (const float*)d_in[3];
  const float* Wv = (const float*)d_in[4];
  const float* Wo = (const float*)d_in[5];
  float* out = (float*)d_out;
  char* ws = (char*)d_ws;

  // workspace layout (bytes); attn reuses xb region (disjoint lifetimes). 168 MB total.
  u16* xb = (u16*)(ws);                         // [4096][4096] bf16, 33.5 MB
  u16* Wt = (u16*)(ws + 33554432);              // [6144][4096] bf16 (Wq^T|Wk^T|Wv^T), 50.3 MB
  u16* WoT = (u16*)(ws + 83886080);             // [4096][4096] bf16 (Wo^T), 33.5 MB
  u16* qkv = (u16*)(ws + 117440512);            // [4096][6144] bf16, 50.3 MB
  u16* attn = xb;                               // [4096][4096] bf16 (after x consumed)

  cvt_kernel<<<16384, 256, 0, stream>>>((const float4*)x, (uint2*)xb, 4194304);
  tcvt_kernel<<<dim3(128, 128), dim3(32, 8), 0, stream>>>(Wq, Wt, 4096, 4096);
  tcvt_kernel<<<dim3(32, 128), dim3(32, 8), 0, stream>>>(Wk, Wt + (size_t)4096 * 4096, 4096, 1024);
  tcvt_kernel<<<dim3(32, 128), dim3(32, 8), 0, stream>>>(Wv, Wt + (size_t)5120 * 4096, 4096, 1024);
  tcvt_kernel<<<dim3(128, 128), dim3(32, 8), 0, stream>>>(Wo, WoT, 4096, 4096);

  gemm_nt<1><<<dim3(48, 32), 256, 0, stream>>>(xb, Wt, qkv, 4096, 6144, 4096);
  rope_kernel<<<40960, 256, 0, stream>>>(qkv, posi, 10485760);
  attn_kernel<<<2048, 256, 0, stream>>>(qkv, attn);
  gemm_nt<0><<<dim3(32, 32), 256, 0, stream>>>(attn, WoT, out, 4096, 4096, 4096);
}